// Round 13
// baseline (331.598 us; speedup 1.0000x reference)
//
#include <hip/hip_runtime.h>

#define BB    8
#define LSEQ  4096
#define DD    4096
#define EE    8
#define RR    16
#define KK    2
#define NSLICE 128
#define LORA_SCALE (1.0f / 16.0f)   // ALPHA / R
#define LN_EPS 1e-5f

typedef float f4 __attribute__((ext_vector_type(4)));

__device__ __forceinline__ float wave_sum(float v) {
#pragma unroll
    for (int off = 32; off > 0; off >>= 1)
        v += __shfl_xor(v, off, 64);
    return v;
}

__device__ __forceinline__ float dot4(f4 a, f4 b) {
    return a.x * b.x + a.y * b.y + a.z * b.z + a.w * b.w;
}

// ---------------------------------------------------------------------------
// Kernel 1: proven roofline version (87us, 6.1 TB/s). 1024 blocks x 32 rows.
// ---------------------------------------------------------------------------
__global__ __launch_bounds__(256) void colsum_kernel(
    const f4* __restrict__ x, f4* __restrict__ partial, int rows_per_slice)
{
    const int tid = threadIdx.x;
    const int bid = blockIdx.x;
    const int b  = bid >> 7;           // / NSLICE
    const int sl = bid & (NSLICE - 1);
    const f4* p = x + ((size_t)b * LSEQ + (size_t)sl * rows_per_slice) * (DD / 4);

    f4 acc[4];
#pragma unroll
    for (int i = 0; i < 4; ++i) acc[i] = (f4)(0.f);

#pragma unroll 2
    for (int l = 0; l < rows_per_slice; ++l) {
        const f4* pr = p + (size_t)l * (DD / 4);
#pragma unroll
        for (int i = 0; i < 4; ++i)
            acc[i] += __builtin_nontemporal_load(&pr[tid + i * 256]);
    }
    f4* dst = partial + ((size_t)sl * BB + b) * (DD / 4);
#pragma unroll
    for (int i = 0; i < 4; ++i) dst[tid + i * 256] = acc[i];
}

// ---------------------------------------------------------------------------
// Kernel 2: router (top-2 softmax) + LoRA delta, 1024 threads per b. (~15us)
// ---------------------------------------------------------------------------
__global__ __launch_bounds__(1024) void router_delta_kernel(
    const f4* __restrict__ partial, int nslice,
    const f4* __restrict__ gate_w, const float* __restrict__ gate_b,
    const f4* __restrict__ A_w, const f4* __restrict__ B_w,
    f4* __restrict__ delta)
{
    __shared__ float redl[EE * 16];
    __shared__ float lgbuf[EE];
    __shared__ float redz[KK * RR * 16];
    __shared__ float zbuf[KK * RR];
    __shared__ int   sel[KK];
    __shared__ float wsel[KK];

    const int b = blockIdx.x;
    const int tid = threadIdx.x;
    const int lane = tid & 63;
    const int wid = tid >> 6;

    f4 acc = (f4)(0.f);
#pragma unroll 8
    for (int sl = 0; sl < nslice; ++sl)
        acc += partial[((size_t)sl * BB + b) * (DD / 4) + tid];
    const f4 h = acc * (1.0f / LSEQ);

#pragma unroll
    for (int e = 0; e < EE; ++e) {
        float s = wave_sum(dot4(h, gate_w[e * (DD / 4) + tid]));
        if (lane == 0) redl[e * 16 + wid] = s;
    }
    __syncthreads();
    if (tid < EE) {
        float s = 0.f;
#pragma unroll
        for (int w = 0; w < 16; ++w) s += redl[tid * 16 + w];
        lgbuf[tid] = s + gate_b[tid];
    }
    __syncthreads();
    if (tid == 0) {
        int i0 = 0;
        for (int e = 1; e < EE; ++e) if (lgbuf[e] > lgbuf[i0]) i0 = e;  // ties -> lowest idx
        int i1 = (i0 == 0) ? 1 : 0;
        for (int e = 0; e < EE; ++e) if (e != i0 && lgbuf[e] > lgbuf[i1]) i1 = e;
        float e1 = __expf(lgbuf[i1] - lgbuf[i0]);
        float inv = 1.0f / (1.0f + e1);
        sel[0] = i0; sel[1] = i1;
        wsel[0] = inv; wsel[1] = e1 * inv;
    }
    __syncthreads();

    const f4* A0 = A_w + (size_t)sel[0] * RR * (DD / 4);
    const f4* A1 = A_w + (size_t)sel[1] * RR * (DD / 4);
#pragma unroll
    for (int r = 0; r < RR; ++r) {
        float s0 = wave_sum(dot4(h, A0[r * (DD / 4) + tid]));
        float s1 = wave_sum(dot4(h, A1[r * (DD / 4) + tid]));
        if (lane == 0) {
            redz[r * 16 + wid] = s0;
            redz[(RR + r) * 16 + wid] = s1;
        }
    }
    __syncthreads();
    if (tid < KK * RR) {
        float s = 0.f;
#pragma unroll
        for (int w = 0; w < 16; ++w) s += redz[tid * 16 + w];
        zbuf[tid] = s;
    }
    __syncthreads();

    const float w0 = wsel[0], w1 = wsel[1];
    const f4* B0 = B_w + (size_t)sel[0] * DD * (RR / 4);
    const f4* B1 = B_w + (size_t)sel[1] * DD * (RR / 4);
    f4 o;
#pragma unroll
    for (int c = 0; c < 4; ++c) {
        const int d = tid * 4 + c;
        float s0 = 0.f, s1 = 0.f;
#pragma unroll
        for (int rv = 0; rv < RR / 4; ++rv) {
            f4 b0 = B0[d * (RR / 4) + rv];
            f4 b1 = B1[d * (RR / 4) + rv];
            s0 += b0.x * zbuf[rv * 4] + b0.y * zbuf[rv * 4 + 1]
                + b0.z * zbuf[rv * 4 + 2] + b0.w * zbuf[rv * 4 + 3];
            s1 += b1.x * zbuf[RR + rv * 4] + b1.y * zbuf[RR + rv * 4 + 1]
                + b1.z * zbuf[RR + rv * 4 + 2] + b1.w * zbuf[RR + rv * 4 + 3];
        }
        float v = LORA_SCALE * (w0 * s0 + w1 * s1);
        if (c == 0) o.x = v; else if (c == 1) o.y = v; else if (c == 2) o.z = v; else o.w = v;
    }
    delta[(size_t)b * (DD / 4) + tid] = o;
}

// ---------------------------------------------------------------------------
// Kernel 3 v6: 8 rows per block; wave w owns column-quarter w of all 8 rows.
// delta/gamma/beta quarter loaded ONCE into registers (12 f4), reused for
// 8 rows -> cached const traffic 6KB/row. 32 x nt-loads issued up front;
// one __syncthreads + 512B LDS merges quarter partials for all 8 rows.
// ~190 VGPRs (no spill per m08's 450 bound); occupancy-insensitive per R9.
// ---------------------------------------------------------------------------
__global__ __launch_bounds__(256) void resid_ln_kernel6(
    const f4* __restrict__ x, const f4* __restrict__ delta,
    const f4* __restrict__ gamma, const f4* __restrict__ beta,
    f4* __restrict__ out)
{
    __shared__ float redS[8][4], redQ[8][4];
    const int tid = threadIdx.x;
    const int lane = tid & 63, w = tid >> 6;          // w = column quarter
    const int rp = (int)(gridDim.x - 1 - blockIdx.x); // tail-first (L3 residue)
    const size_t row0 = (size_t)rp * 8;
    const int b = (int)(row0 >> 12);                  // LSEQ = 4096, 8 | 4096
    const int qbase = w * 256;                        // f4 offset of quarter
    const f4* dr = delta + (size_t)b * (DD / 4) + qbase;
    const f4* gr = gamma + qbase;
    const f4* br = beta + qbase;

    // row-invariant quarter constants: 12 f4 in registers
    f4 dv[4], gv[4], bv[4];
#pragma unroll
    for (int j = 0; j < 4; ++j) {
        const int idx = lane + j * 64;
        dv[j] = dr[idx];
        gv[j] = gr[idx];
        bv[j] = br[idx];
    }

    // all 32 x nt-loads in flight
    f4 v[8][4];
#pragma unroll
    for (int r = 0; r < 8; ++r) {
        const f4* xr = x + (row0 + r) * (DD / 4) + qbase;
#pragma unroll
        for (int j = 0; j < 4; ++j)
            v[r][j] = __builtin_nontemporal_load(&xr[lane + j * 64]);
    }

    // per-row quarter sums
#pragma unroll
    for (int r = 0; r < 8; ++r) {
        float s = 0.f, q = 0.f;
#pragma unroll
        for (int j = 0; j < 4; ++j) {
            f4 xv = v[r][j] + dv[j];
            v[r][j] = xv;
            s += xv.x + xv.y + xv.z + xv.w;
            q += xv.x * xv.x + xv.y * xv.y + xv.z * xv.z + xv.w * xv.w;
        }
        s = wave_sum(s);
        q = wave_sum(q);
        if (lane == 0) { redS[r][w] = s; redQ[r][w] = q; }
    }
    __syncthreads();

#pragma unroll
    for (int r = 0; r < 8; ++r) {
        const float S = redS[r][0] + redS[r][1] + redS[r][2] + redS[r][3];
        const float Q = redQ[r][0] + redQ[r][1] + redQ[r][2] + redQ[r][3];
        const float mean = S * (1.0f / DD);
        const float var  = Q * (1.0f / DD) - mean * mean;
        const float rstd = rsqrtf(var + LN_EPS);
        f4* orow = out + (row0 + r) * (DD / 4) + qbase;
#pragma unroll
        for (int j = 0; j < 4; ++j) {
            f4 xv = v[r][j];
            f4 o;
            o.x = (xv.x - mean) * rstd * gv[j].x + bv[j].x;
            o.y = (xv.y - mean) * rstd * gv[j].y + bv[j].y;
            o.z = (xv.z - mean) * rstd * gv[j].z + bv[j].z;
            o.w = (xv.w - mean) * rstd * gv[j].w + bv[j].w;
            __builtin_nontemporal_store(o, &orow[lane + j * 64]);
        }
    }
}

extern "C" void kernel_launch(void* const* d_in, const int* in_sizes, int n_in,
                              void* d_out, int out_size, void* d_ws, size_t ws_size,
                              hipStream_t stream) {
    const f4* x       = (const f4*)d_in[0];
    const f4* gate_w  = (const f4*)d_in[1];
    const float* gate_b = (const float*)d_in[2];
    const f4* A_w     = (const f4*)d_in[3];
    const f4* B_w     = (const f4*)d_in[4];
    const f4* gamma   = (const f4*)d_in[5];
    const f4* beta    = (const f4*)d_in[6];
    f4* out = (f4*)d_out;
    float* ws = (float*)d_ws;

    f4* partial = (f4*)ws;
    f4* delta   = (f4*)(ws + (size_t)NSLICE * BB * DD);

    colsum_kernel<<<BB * NSLICE, 256, 0, stream>>>(
        x, partial, LSEQ / NSLICE);

    router_delta_kernel<<<BB, 1024, 0, stream>>>(
        partial, NSLICE, gate_w, gate_b, A_w, B_w, delta);

    resid_ln_kernel6<<<BB * LSEQ / 8, 256, 0, stream>>>(
        x, delta, gamma, beta, out);
}

// Round 14
// 315.272 us; speedup vs baseline: 1.0518x; 1.0518x over previous
//
#include <hip/hip_runtime.h>

#define BB    8
#define LSEQ  4096
#define DD    4096
#define EE    8
#define RR    16
#define KK    2
#define NSLICE 128
#define LORA_SCALE (1.0f / 16.0f)   // ALPHA / R
#define LN_EPS 1e-5f

typedef float f4 __attribute__((ext_vector_type(4)));

__device__ __forceinline__ float wave_sum(float v) {
#pragma unroll
    for (int off = 32; off > 0; off >>= 1)
        v += __shfl_xor(v, off, 64);
    return v;
}

__device__ __forceinline__ float dot4(f4 a, f4 b) {
    return a.x * b.x + a.y * b.y + a.z * b.z + a.w * b.w;
}

// ---------------------------------------------------------------------------
// Kernel 1: proven roofline version (87us, 6.1 TB/s). 1024 blocks x 32 rows.
// ---------------------------------------------------------------------------
__global__ __launch_bounds__(256) void colsum_kernel(
    const f4* __restrict__ x, f4* __restrict__ partial, int rows_per_slice)
{
    const int tid = threadIdx.x;
    const int bid = blockIdx.x;
    const int b  = bid >> 7;           // / NSLICE
    const int sl = bid & (NSLICE - 1);
    const f4* p = x + ((size_t)b * LSEQ + (size_t)sl * rows_per_slice) * (DD / 4);

    f4 acc[4];
#pragma unroll
    for (int i = 0; i < 4; ++i) acc[i] = (f4)(0.f);

#pragma unroll 2
    for (int l = 0; l < rows_per_slice; ++l) {
        const f4* pr = p + (size_t)l * (DD / 4);
#pragma unroll
        for (int i = 0; i < 4; ++i)
            acc[i] += __builtin_nontemporal_load(&pr[tid + i * 256]);
    }
    f4* dst = partial + ((size_t)sl * BB + b) * (DD / 4);
#pragma unroll
    for (int i = 0; i < 4; ++i) dst[tid + i * 256] = acc[i];
}

// ---------------------------------------------------------------------------
// Kernel 1b (NEW): fold 128 slice-partials -> pooled h[b][d] on 32 blocks
// (4x the CU-parallelism of K2's old 8-block pooling read of 16 MB).
// grid (4, 8): block (c, b) reduces f4 columns c*256..c*256+255.
// ---------------------------------------------------------------------------
__global__ __launch_bounds__(256) void pool_reduce_kernel(
    const f4* __restrict__ partial, f4* __restrict__ hbuf)
{
    const int t = threadIdx.x;
    const int c = blockIdx.x;          // 0..3
    const int b = blockIdx.y;          // 0..7
    const int col = c * 256 + t;       // f4 column
    f4 acc = (f4)(0.f);
#pragma unroll 8
    for (int sl = 0; sl < NSLICE; ++sl)
        acc += partial[((size_t)sl * BB + b) * (DD / 4) + col];
    hbuf[(size_t)b * (DD / 4) + col] = acc * (1.0f / LSEQ);
}

// ---------------------------------------------------------------------------
// Kernel 2 (slim): router (top-2 softmax) + LoRA delta; pooling phase is now
// a single f4 load of the precomputed h.
// ---------------------------------------------------------------------------
__global__ __launch_bounds__(1024) void router_delta_kernel(
    const f4* __restrict__ hbuf,
    const f4* __restrict__ gate_w, const float* __restrict__ gate_b,
    const f4* __restrict__ A_w, const f4* __restrict__ B_w,
    f4* __restrict__ delta)
{
    __shared__ float redl[EE * 16];
    __shared__ float lgbuf[EE];
    __shared__ float redz[KK * RR * 16];
    __shared__ float zbuf[KK * RR];
    __shared__ int   sel[KK];
    __shared__ float wsel[KK];

    const int b = blockIdx.x;
    const int tid = threadIdx.x;          // == f4 column index, 0..1023
    const int lane = tid & 63;
    const int wid = tid >> 6;             // 0..15

    const f4 h = hbuf[(size_t)b * (DD / 4) + tid];

#pragma unroll
    for (int e = 0; e < EE; ++e) {
        float s = wave_sum(dot4(h, gate_w[e * (DD / 4) + tid]));
        if (lane == 0) redl[e * 16 + wid] = s;
    }
    __syncthreads();
    if (tid < EE) {
        float s = 0.f;
#pragma unroll
        for (int w = 0; w < 16; ++w) s += redl[tid * 16 + w];
        lgbuf[tid] = s + gate_b[tid];
    }
    __syncthreads();
    if (tid == 0) {
        int i0 = 0;
        for (int e = 1; e < EE; ++e) if (lgbuf[e] > lgbuf[i0]) i0 = e;  // ties -> lowest idx
        int i1 = (i0 == 0) ? 1 : 0;
        for (int e = 0; e < EE; ++e) if (e != i0 && lgbuf[e] > lgbuf[i1]) i1 = e;
        float e1 = __expf(lgbuf[i1] - lgbuf[i0]);
        float inv = 1.0f / (1.0f + e1);
        sel[0] = i0; sel[1] = i1;
        wsel[0] = inv; wsel[1] = e1 * inv;
    }
    __syncthreads();

    const f4* A0 = A_w + (size_t)sel[0] * RR * (DD / 4);
    const f4* A1 = A_w + (size_t)sel[1] * RR * (DD / 4);
#pragma unroll
    for (int r = 0; r < RR; ++r) {
        float s0 = wave_sum(dot4(h, A0[r * (DD / 4) + tid]));
        float s1 = wave_sum(dot4(h, A1[r * (DD / 4) + tid]));
        if (lane == 0) {
            redz[r * 16 + wid] = s0;
            redz[(RR + r) * 16 + wid] = s1;
        }
    }
    __syncthreads();
    if (tid < KK * RR) {
        float s = 0.f;
#pragma unroll
        for (int w = 0; w < 16; ++w) s += redz[tid * 16 + w];
        zbuf[tid] = s;
    }
    __syncthreads();

    const float w0 = wsel[0], w1 = wsel[1];
    const f4* B0 = B_w + (size_t)sel[0] * DD * (RR / 4);
    const f4* B1 = B_w + (size_t)sel[1] * DD * (RR / 4);
    f4 o;
#pragma unroll
    for (int c = 0; c < 4; ++c) {
        const int d = tid * 4 + c;
        float s0 = 0.f, s1 = 0.f;
#pragma unroll
        for (int rv = 0; rv < RR / 4; ++rv) {
            f4 b0 = B0[d * (RR / 4) + rv];
            f4 b1 = B1[d * (RR / 4) + rv];
            s0 += b0.x * zbuf[rv * 4] + b0.y * zbuf[rv * 4 + 1]
                + b0.z * zbuf[rv * 4 + 2] + b0.w * zbuf[rv * 4 + 3];
            s1 += b1.x * zbuf[RR + rv * 4] + b1.y * zbuf[RR + rv * 4 + 1]
                + b1.z * zbuf[RR + rv * 4 + 2] + b1.w * zbuf[RR + rv * 4 + 3];
        }
        float v = LORA_SCALE * (w0 * s0 + w1 * s1);
        if (c == 0) o.x = v; else if (c == 1) o.y = v; else if (c == 2) o.z = v; else o.w = v;
    }
    delta[(size_t)b * (DD / 4) + tid] = o;
}

// ---------------------------------------------------------------------------
// Kernel 3: EXACT R12 version (best measured: ~213us). 4 rows per block;
// wave w owns column-quarter w of all 4 rows; delta/gamma/beta quarter in
// registers reused 4x; 16 x nt-loads up front; one barrier, 128B LDS merge.
// ---------------------------------------------------------------------------
__global__ __launch_bounds__(256) void resid_ln_kernel4(
    const f4* __restrict__ x, const f4* __restrict__ delta,
    const f4* __restrict__ gamma, const f4* __restrict__ beta,
    f4* __restrict__ out)
{
    __shared__ float redS[4][4], redQ[4][4];
    const int tid = threadIdx.x;
    const int lane = tid & 63, w = tid >> 6;          // w = column quarter
    const int rp = (int)(gridDim.x - 1 - blockIdx.x); // tail-first
    const size_t row0 = (size_t)rp * 4;
    const int b = (int)(row0 >> 12);                  // LSEQ = 4096
    const int qbase = w * 256;                        // f4 offset of quarter
    const f4* dr = delta + (size_t)b * (DD / 4) + qbase;
    const f4* gr = gamma + qbase;
    const f4* br = beta + qbase;

    // row-invariant quarter constants: 12 f4 in registers
    f4 dv[4], gv[4], bv[4];
#pragma unroll
    for (int j = 0; j < 4; ++j) {
        const int idx = lane + j * 64;
        dv[j] = dr[idx];
        gv[j] = gr[idx];
        bv[j] = br[idx];
    }

    // all 16 x nt-loads in flight
    f4 v[4][4];
#pragma unroll
    for (int r = 0; r < 4; ++r) {
        const f4* xr = x + (row0 + r) * (DD / 4) + qbase;
#pragma unroll
        for (int j = 0; j < 4; ++j)
            v[r][j] = __builtin_nontemporal_load(&xr[lane + j * 64]);
    }

    // per-row quarter sums
#pragma unroll
    for (int r = 0; r < 4; ++r) {
        float s = 0.f, q = 0.f;
#pragma unroll
        for (int j = 0; j < 4; ++j) {
            f4 xv = v[r][j] + dv[j];
            v[r][j] = xv;
            s += xv.x + xv.y + xv.z + xv.w;
            q += xv.x * xv.x + xv.y * xv.y + xv.z * xv.z + xv.w * xv.w;
        }
        s = wave_sum(s);
        q = wave_sum(q);
        if (lane == 0) { redS[r][w] = s; redQ[r][w] = q; }
    }
    __syncthreads();

#pragma unroll
    for (int r = 0; r < 4; ++r) {
        const float S = redS[r][0] + redS[r][1] + redS[r][2] + redS[r][3];
        const float Q = redQ[r][0] + redQ[r][1] + redQ[r][2] + redQ[r][3];
        const float mean = S * (1.0f / DD);
        const float var  = Q * (1.0f / DD) - mean * mean;
        const float rstd = rsqrtf(var + LN_EPS);
        f4* orow = out + (row0 + r) * (DD / 4) + qbase;
#pragma unroll
        for (int j = 0; j < 4; ++j) {
            f4 xv = v[r][j];
            f4 o;
            o.x = (xv.x - mean) * rstd * gv[j].x + bv[j].x;
            o.y = (xv.y - mean) * rstd * gv[j].y + bv[j].y;
            o.z = (xv.z - mean) * rstd * gv[j].z + bv[j].z;
            o.w = (xv.w - mean) * rstd * gv[j].w + bv[j].w;
            __builtin_nontemporal_store(o, &orow[lane + j * 64]);
        }
    }
}

extern "C" void kernel_launch(void* const* d_in, const int* in_sizes, int n_in,
                              void* d_out, int out_size, void* d_ws, size_t ws_size,
                              hipStream_t stream) {
    const f4* x       = (const f4*)d_in[0];
    const f4* gate_w  = (const f4*)d_in[1];
    const float* gate_b = (const float*)d_in[2];
    const f4* A_w     = (const f4*)d_in[3];
    const f4* B_w     = (const f4*)d_in[4];
    const f4* gamma   = (const f4*)d_in[5];
    const f4* beta    = (const f4*)d_in[6];
    f4* out = (f4*)d_out;
    float* ws = (float*)d_ws;

    f4* partial = (f4*)ws;                                        // 16 MB
    f4* hbuf    = (f4*)(ws + (size_t)NSLICE * BB * DD);           // 128 KB
    f4* delta   = (f4*)(ws + (size_t)NSLICE * BB * DD + BB * DD); // 128 KB

    colsum_kernel<<<BB * NSLICE, 256, 0, stream>>>(
        x, partial, LSEQ / NSLICE);

    pool_reduce_kernel<<<dim3(4, BB), 256, 0, stream>>>(partial, hbuf);

    router_delta_kernel<<<BB, 1024, 0, stream>>>(
        hbuf, gate_w, gate_b, A_w, B_w, delta);

    resid_ln_kernel4<<<BB * LSEQ / 4, 256, 0, stream>>>(
        x, delta, gamma, beta, out);
}